// Round 7
// baseline (446.427 us; speedup 1.0000x reference)
//
#include <hip/hip_runtime.h>

#define N_NODES 100000
#define E_EDGES 1600000
#define INDIM 256
#define HID 128
#define CAP 64          // per-node adjacency capacity (max degree ~40 for this graph)
#define NPART 8
#define PART_SZ 12500   // N_NODES / NPART
#define ECAP 32768      // per (xcd,part) sub-list capacity; expected ~25000
#define PA_BLOCKS 1563  // 400128 threads x 4 rounds covers 1.6M edges
#define PA_STRIDE (PA_BLOCKS * 256)
#define G1_BLOCKS 1563  // gemm1: ceil(100000/64)
#define CHUNK 125       // dst nodes per chunk
#define NCHUNKS 100     // chunks per partition
#define CCAP 4096       // per-chunk list capacity (avg ~2000, +46 sigma)
#define BINCAP 128      // partd per-block per-bin LDS buffer (avg fill ~62)
#define PD_BLOCKS 256   // partd: 32 blocks x 8 partitions

typedef __attribute__((ext_vector_type(8))) short s16x8;
typedef __attribute__((ext_vector_type(4))) float f32x4;
typedef __attribute__((ext_vector_type(4))) unsigned int u32x4;

// ---- bf16 helpers (explicit RNE, bit-level) ----
__device__ __forceinline__ unsigned short cvt_bf16(float f) {
    unsigned int u = __float_as_uint(f);
    u += 0x7FFFu + ((u >> 16) & 1u);
    return (unsigned short)(u >> 16);
}
__device__ __forceinline__ float bf16_to_f(unsigned short s) {
    return __uint_as_float(((unsigned int)s) << 16);
}

// ---------------- prep weights + zero count/gcnt/ccnt (one launch) ----------------
__global__ __launch_bounds__(256) void prepzero_kernel(const float* __restrict__ Wc,
                                                       const float* __restrict__ Wl,
                                                       unsigned short* __restrict__ f1,
                                                       unsigned short* __restrict__ f2,
                                                       int* __restrict__ count) {
    const int b = blockIdx.x;
    const int tid = threadIdx.x;
    if (b < 256) {
        int pt = b * 256 + tid;  // 0..65535
        if (pt < 32768) {
            int j = pt & 7, L = (pt >> 3) & 63, t = (pt >> 9) & 7, c = pt >> 12;
            int k = c * 32 + ((L >> 4) * 8) + j;
            int n = t * 16 + (L & 15);
            f1[pt] = cvt_bf16(Wc[k * 128 + n]);
        } else {
            int u = pt - 32768;
            int j = u & 7, L = (u >> 3) & 63, t = (u >> 9) & 15, c = u >> 13;
            int k = c * 32 + ((L >> 4) * 8) + j;
            int n = t * 16 + (L & 15);
            f2[u] = cvt_bf16(Wl[k * 256 + n]);
        }
    } else {
        // zero count[100000] + gcnt[64] + ccnt[800]  (= 100864 ints)
        for (int i = (b - 256) * 256 + tid; i < 100864; i += 256 * 256) count[i] = 0;
    }
}

// ---------------- fatA: parta (blocks 0..1562) || gemm1 (blocks 1563..3125) ----------
// parta: single edge scan; packs (local_dst<<17 | src) into 64 sub-lists
// [xcd][part] (ballot-aggregated contiguous appends, XCD-local gcnt atomics)
// + fire-and-forget degree atomics into count[] (no return -> no stall chain).
// gemm1: h_bf16 = bf16(x) @ bf16(W_conv), x streamed nontemporal.
__global__ __launch_bounds__(256) void fata_kernel(const int* __restrict__ src,
                                                   const int* __restrict__ dst,
                                                   int* __restrict__ gcnt,
                                                   unsigned int* __restrict__ pedges,
                                                   int* __restrict__ count,
                                                   const float* __restrict__ x,
                                                   const unsigned short* __restrict__ fragW,
                                                   unsigned short* __restrict__ h) {
    __shared__ __align__(16) unsigned short xs[64 * 48];
    __shared__ int sCount[8];
    __shared__ int sBase[8];
    const int tid = threadIdx.x;

    if (blockIdx.x < PA_BLOCKS) {
        // ---- parta ----
        if (tid < 8) sCount[tid] = 0;
        __syncthreads();
        const int lane = tid & 63;
        const int t0 = blockIdx.x * 256 + tid;
        const int xcd = blockIdx.x & 7;

        unsigned int pk[4];
        int pp[4];
        int lo[4];
#pragma unroll
        for (int r = 0; r < 4; ++r) {
            int e = t0 + r * PA_STRIDE;
            bool valid = e < E_EDGES;
            int d = 0, s = 0;
            if (valid) {
                d = __builtin_nontemporal_load(dst + e);
                s = __builtin_nontemporal_load(src + e);
            }
            if (valid) atomicAdd(&count[d], 1);   // degree; no return used
            int p = valid ? d / PART_SZ : 8;
            unsigned long long mask_p = 0ull;
#pragma unroll
            for (int v = 0; v < 8; ++v) {
                unsigned long long mv = __ballot(p == v);
                if (p == v) mask_p = mv;
            }
            int off = __popcll(mask_p & ((1ull << lane) - 1ull));
            int ldr = (mask_p == 0ull) ? 0 : (__ffsll(mask_p) - 1);
            int wbase = 0;
            if (valid && lane == ldr) wbase = atomicAdd(&sCount[p], __popcll(mask_p));
            wbase = __shfl(wbase, ldr);
            pp[r] = p;
            lo[r] = wbase + off;
            pk[r] = ((unsigned int)(d - p * PART_SZ) << 17) | (unsigned int)s;
        }
        __syncthreads();
        if (tid < 8) sBase[tid] = atomicAdd(&gcnt[xcd * 8 + tid], sCount[tid]);
        __syncthreads();
#pragma unroll
        for (int r = 0; r < 4; ++r) {
            if (pp[r] < 8) {
                int pos = sBase[pp[r]] + lo[r];
                if (pos < ECAP)
                    __builtin_nontemporal_store(pk[r],
                        pedges + (size_t)(xcd * 8 + pp[r]) * ECAP + pos);
            }
        }
    } else {
        // ---- gemm1 ----
        const int r0 = (blockIdx.x - PA_BLOCKS) * 64;
        const int w = tid >> 6, lane = tid & 63;
        const int q = lane >> 4, m = lane & 15;
        const int srow = tid >> 2, skg = tid & 3;

        f32x4 acc[8];
#pragma unroll
        for (int t = 0; t < 8; ++t) acc[t] = (f32x4){0.f, 0.f, 0.f, 0.f};

        const s16x8* fwv = (const s16x8*)fragW;

        for (int c = 0; c < 8; ++c) {
            int gr = r0 + srow;
            f32x4 v0 = (f32x4){0.f, 0.f, 0.f, 0.f}, v1 = v0;
            if (gr < N_NODES) {
                const f32x4* p = (const f32x4*)&x[(size_t)gr * INDIM + c * 32 + skg * 8];
                v0 = __builtin_nontemporal_load(p);
                v1 = __builtin_nontemporal_load(p + 1);
            }
            uint4 pk;
            pk.x = ((unsigned)cvt_bf16(v0.y) << 16) | cvt_bf16(v0.x);
            pk.y = ((unsigned)cvt_bf16(v0.w) << 16) | cvt_bf16(v0.z);
            pk.z = ((unsigned)cvt_bf16(v1.y) << 16) | cvt_bf16(v1.x);
            pk.w = ((unsigned)cvt_bf16(v1.w) << 16) | cvt_bf16(v1.z);
            *(uint4*)&xs[srow * 48 + skg * 8] = pk;
            __syncthreads();

            s16x8 a = *(const s16x8*)&xs[(w * 16 + m) * 48 + q * 8];
#pragma unroll
            for (int t = 0; t < 8; ++t) {
                s16x8 b = fwv[(c * 8 + t) * 64 + lane];
                acc[t] = __builtin_amdgcn_mfma_f32_16x16x32_bf16(a, b, acc[t], 0, 0, 0);
            }
            __syncthreads();
        }

        const int row_base = r0 + w * 16 + q * 4;
#pragma unroll
        for (int t = 0; t < 8; ++t) {
#pragma unroll
            for (int r = 0; r < 4; ++r) {
                int row = row_base + r;
                if (row < N_NODES)
                    __builtin_nontemporal_store(cvt_bf16(acc[t][r]),
                        h + (size_t)row * HID + t * 16 + m);
            }
        }
    }
}

// ---------------- partd: LDS-buffered radix, partition sub-lists -> 100 chunk-lists ----
// Block = (part, 1-of-32 slice). Deposits into 100 LDS bins (avg fill 62/128),
// then ONE flush: per-bin global cursor atomic + contiguous copy. All global
// writes are >=~248B runs -> no write amplification (vs partb's 63MB dirty lines).
__global__ __launch_bounds__(256) void partd_kernel(const unsigned int* __restrict__ pedges,
                                                    const int* __restrict__ gcnt,
                                                    int* __restrict__ ccnt,
                                                    unsigned int* __restrict__ clists) {
    __shared__ unsigned int sBuf[NCHUNKS * BINCAP];   // 51.2 KB
    __shared__ int sCnt[NCHUNKS];
    __shared__ int sBase[NCHUNKS];
    const int tid = threadIdx.x;
    const int part = blockIdx.x & 7;
    const int bslot = blockIdx.x >> 3;   // 0..31

    for (int b = tid; b < NCHUNKS; b += 256) sCnt[b] = 0;
    __syncthreads();

    for (int xx = 0; xx < 8; ++xx) {
        int n = gcnt[xx * 8 + part];
        if (n > ECAP) n = ECAP;
        const unsigned int* lst = pedges + (size_t)(xx * 8 + part) * ECAP;
        for (int i = bslot * 256 + tid; i < n; i += (PD_BLOCKS / 8) * 256) {
            unsigned int v = __builtin_nontemporal_load(lst + i);
            int bin = (int)(v >> 17) / CHUNK;            // 0..99
            int pos = atomicAdd(&sCnt[bin], 1);
            if (pos < BINCAP) {
                sBuf[bin * BINCAP + pos] = v;
            } else {                                      // rare overflow: direct append
                int gp = atomicAdd(&ccnt[part * NCHUNKS + bin], 1);
                if (gp < CCAP)
                    clists[(size_t)(part * NCHUNKS + bin) * CCAP + gp] = v;
            }
        }
    }
    __syncthreads();

    if (tid < NCHUNKS) {
        int c = sCnt[tid]; if (c > BINCAP) c = BINCAP;
        sBase[tid] = atomicAdd(&ccnt[part * NCHUNKS + tid], c);
        sCnt[tid] = c;
    }
    __syncthreads();

    const int wv = tid >> 6, lane = tid & 63;
    for (int b = wv; b < NCHUNKS; b += 4) {
        int c = sCnt[b];
        int base = sBase[b];
        unsigned int* dstp = clists + (size_t)(part * NCHUNKS + b) * CCAP;
        for (int i = lane; i < c; i += 64) {
            int gp = base + i;
            if (gp < CCAP) dstp[gp] = sBuf[b * BINCAP + i];
        }
    }
}

// ---------------- bgather: LDS adjacency + wave-per-node gather, fused ----------------
// Block = (part, chunk of 125 nodes). Phase 1: deposit the chunk's ~2000-edge
// list into s_adj[125][64] via LDS-atomic slots (replaces the 63MB global bucket
// scatter). Phase 2: proven wave-per-node gather loop, adjacency from LDS,
// 16 edges in flight per wave (4 independent uint4 row loads per lane).
__global__ __launch_bounds__(1024, 8) void bgather_kernel(const unsigned int* __restrict__ clists,
                                                          const int* __restrict__ ccnt,
                                                          const int* __restrict__ count,
                                                          const unsigned short* __restrict__ h,
                                                          const float* __restrict__ b_conv,
                                                          const float* __restrict__ prelu_a,
                                                          unsigned short* __restrict__ agg) {
    __shared__ int s_adj[CHUNK * CAP];   // 32 KB
    __shared__ int s_cnt[CHUNK];
    const int tid = threadIdx.x;
    const int part = blockIdx.x & 7;     // dst partition == XCD (round-robin heuristic)
    const int c = blockIdx.x >> 3;       // 0..99
    const int node0 = part * PART_SZ + c * CHUNK;

    if (tid < CHUNK) s_cnt[tid] = 0;
    __syncthreads();

    int m = ccnt[part * NCHUNKS + c]; if (m > CCAP) m = CCAP;
    const unsigned int* lst = clists + (size_t)(part * NCHUNKS + c) * CCAP;
    for (int i = tid; i < m; i += 1024) {
        unsigned int v = lst[i];
        int dl = (int)(v >> 17) - c * CHUNK;             // 0..124
        int slot = atomicAdd(&s_cnt[dl], 1);
        if (slot < CAP) s_adj[dl * CAP + slot] = (int)(v & 0x1FFFFu);
    }
    __syncthreads();

    const int wv = tid >> 6;             // 0..15
    const int lane = tid & 63;
    const int g = lane >> 4;
    const int l = lane & 15;
    const uint4* hp4 = (const uint4*)h;  // one row = 16 uint4

    const float a = prelu_a[0];
    const float4 b0 = *(const float4*)&b_conv[l * 8];
    const float4 b1 = *(const float4*)&b_conv[l * 8 + 4];

    for (int n = wv; n < CHUNK; n += 16) {
        const int wid = node0 + n;
        const int raw = s_cnt[n];
        const float dn = rsqrtf((float)(raw + 1));
        int deg = raw > CAP ? CAP : raw;

        // preload: lane j holds edge j's (src, dinv); pad lanes -> (wid, 0)
        int s_l = wid;
        float dv_l = 0.f;
        if (lane < deg) {
            s_l = s_adj[n * CAP + lane];
            dv_l = rsqrtf((float)(count[s_l] + 1));
        }

        float acc[8];
        {   // self-loop: counted once via group 0
            uint4 hv = hp4[(size_t)wid * 16 + l];
            float w0 = (g == 0) ? dn * dn : 0.f;
            const unsigned int* pv = (const unsigned int*)&hv;
#pragma unroll
            for (int k = 0; k < 4; ++k) {
                acc[2 * k]     = w0 * bf16_to_f((unsigned short)(pv[k] & 0xFFFF));
                acc[2 * k + 1] = w0 * bf16_to_f((unsigned short)(pv[k] >> 16));
            }
        }

        for (int j = 0; j < deg; j += 16) {
            int e0 = j + g;                       // all <= 63 since deg <= 64
            int e1 = j + 4 + g;
            int e2 = j + 8 + g;
            int e3 = j + 12 + g;
            int s0 = __shfl(s_l, e0);
            int s1 = __shfl(s_l, e1);
            int s2 = __shfl(s_l, e2);
            int s3 = __shfl(s_l, e3);
            float w0 = __shfl(dv_l, e0) * dn;     // 0 for e >= deg
            float w1 = __shfl(dv_l, e1) * dn;
            float w2 = __shfl(dv_l, e2) * dn;
            float w3 = __shfl(dv_l, e3) * dn;
            uint4 hv0 = hp4[(size_t)s0 * 16 + l];
            uint4 hv1 = hp4[(size_t)s1 * 16 + l];
            uint4 hv2 = hp4[(size_t)s2 * 16 + l];
            uint4 hv3 = hp4[(size_t)s3 * 16 + l];
            const unsigned int* p0 = (const unsigned int*)&hv0;
            const unsigned int* p1 = (const unsigned int*)&hv1;
            const unsigned int* p2 = (const unsigned int*)&hv2;
            const unsigned int* p3 = (const unsigned int*)&hv3;
#pragma unroll
            for (int k = 0; k < 4; ++k) {
                acc[2 * k]     += w0 * bf16_to_f((unsigned short)(p0[k] & 0xFFFF));
                acc[2 * k + 1] += w0 * bf16_to_f((unsigned short)(p0[k] >> 16));
            }
#pragma unroll
            for (int k = 0; k < 4; ++k) {
                acc[2 * k]     += w1 * bf16_to_f((unsigned short)(p1[k] & 0xFFFF));
                acc[2 * k + 1] += w1 * bf16_to_f((unsigned short)(p1[k] >> 16));
            }
#pragma unroll
            for (int k = 0; k < 4; ++k) {
                acc[2 * k]     += w2 * bf16_to_f((unsigned short)(p2[k] & 0xFFFF));
                acc[2 * k + 1] += w2 * bf16_to_f((unsigned short)(p2[k] >> 16));
            }
#pragma unroll
            for (int k = 0; k < 4; ++k) {
                acc[2 * k]     += w3 * bf16_to_f((unsigned short)(p3[k] & 0xFFFF));
                acc[2 * k + 1] += w3 * bf16_to_f((unsigned short)(p3[k] >> 16));
            }
        }

        // sum the 4 group-partials (features 8l..8l+7 live in lanes l,l+16,l+32,l+48)
#pragma unroll
        for (int k = 0; k < 8; ++k) {
            acc[k] += __shfl_xor(acc[k], 16);
            acc[k] += __shfl_xor(acc[k], 32);
        }

        if (g == 0) {
            float bc[8] = {b0.x, b0.y, b0.z, b0.w, b1.x, b1.y, b1.z, b1.w};
            unsigned int o[4];
#pragma unroll
            for (int k = 0; k < 4; ++k) {
                float ox = acc[2 * k] + bc[2 * k];
                float oy = acc[2 * k + 1] + bc[2 * k + 1];
                ox = ox >= 0.f ? ox : a * ox;
                oy = oy >= 0.f ? oy : a * oy;
                o[k] = ((unsigned)cvt_bf16(oy) << 16) | cvt_bf16(ox);
            }
            uint4 ov;
            ov.x = o[0]; ov.y = o[1]; ov.z = o[2]; ov.w = o[3];
            ((uint4*)agg)[(size_t)wid * 16 + l] = ov;
        }
    }
}

// ---------------- GEMM2 (MFMA): out = agg_bf16 @ bf16(W_lin) + b_lin ----------------
__global__ __launch_bounds__(256) void gemm2_kernel(const unsigned short* __restrict__ agg,
                                                    const unsigned short* __restrict__ fragW,
                                                    const float* __restrict__ b_lin,
                                                    float* __restrict__ out) {
    __shared__ __align__(16) unsigned short xs[64 * 48];
    const int tid = threadIdx.x;
    const int r0 = blockIdx.x * 64;
    const int w = tid >> 6, lane = tid & 63;
    const int q = lane >> 4, m = lane & 15;
    const int srow = tid >> 2, skg = tid & 3;

    f32x4 acc[16];
#pragma unroll
    for (int t = 0; t < 16; ++t) acc[t] = (f32x4){0.f, 0.f, 0.f, 0.f};

    const s16x8* fwv = (const s16x8*)fragW;
    const u32x4* aggv = (const u32x4*)agg;

    for (int c = 0; c < 4; ++c) {
        int gr = r0 + srow;
        u32x4 pk = (u32x4){0u, 0u, 0u, 0u};
        if (gr < N_NODES) pk = __builtin_nontemporal_load(&aggv[(size_t)gr * 16 + c * 4 + skg]);
        *(u32x4*)&xs[srow * 48 + skg * 8] = pk;
        __syncthreads();

        s16x8 a = *(const s16x8*)&xs[(w * 16 + m) * 48 + q * 8];
#pragma unroll
        for (int t = 0; t < 16; ++t) {
            s16x8 b = fwv[(c * 16 + t) * 64 + lane];
            acc[t] = __builtin_amdgcn_mfma_f32_16x16x32_bf16(a, b, acc[t], 0, 0, 0);
        }
        __syncthreads();
    }

    const int row_base = r0 + w * 16 + q * 4;
#pragma unroll
    for (int t = 0; t < 16; ++t) {
        float bias = b_lin[t * 16 + m];
#pragma unroll
        for (int r = 0; r < 4; ++r) {
            int row = row_base + r;
            if (row < N_NODES)
                __builtin_nontemporal_store(acc[t][r] + bias,
                    out + (size_t)row * INDIM + t * 16 + m);
        }
    }
}

extern "C" void kernel_launch(void* const* d_in, const int* in_sizes, int n_in,
                              void* d_out, int out_size, void* d_ws, size_t ws_size,
                              hipStream_t stream) {
    const float* x       = (const float*)d_in[0];
    const int*   eidx    = (const int*)d_in[1];
    const float* W_conv  = (const float*)d_in[2];
    const float* b_conv  = (const float*)d_in[3];
    const float* prelu_a = (const float*)d_in[4];
    const float* W_lin   = (const float*)d_in[5];
    const float* b_lin   = (const float*)d_in[6];
    float* out = (float*)d_out;

    const int* src = eidx;
    const int* dst = eidx + E_EDGES;

    // workspace layout
    char* base = (char*)d_ws;
    unsigned int* clists = (unsigned int*)base;                   // 800*4096*4B = 13.1 MB
    unsigned short* agg = (unsigned short*)(base + (size_t)N_NODES * CAP * 4); // at +25.6 MB
    int*   count  = (int*)((char*)agg + (size_t)N_NODES * HID * 2);            // 100000 ints
    int*   gcnt   = count + 100000;                                // 64 ints
    int*   ccnt   = count + 100064;                                // 800 ints
    unsigned short* fragW1 = (unsigned short*)(count + 101120);    // 32768 bf16
    unsigned short* fragW2 = fragW1 + 32768;                       // 32768 bf16
    // Phase-A scratch: 64 sub-lists of ECAP uint32 = 8.39MB, aliases agg
    // (pedges dead after partd; bgather then writes agg; same-stream ordering).
    unsigned int* pedges = (unsigned int*)agg;

    // h_bf16 lives in d_out (25.6 MB of 102.4 MB); gemm2 overwrites out last
    unsigned short* h = (unsigned short*)d_out;

    prepzero_kernel<<<512, 256, 0, stream>>>(W_conv, W_lin, fragW1, fragW2, count);

    fata_kernel<<<PA_BLOCKS + G1_BLOCKS, 256, 0, stream>>>(src, dst, gcnt, pedges,
                                                           count, x, fragW1, h);

    partd_kernel<<<PD_BLOCKS, 256, 0, stream>>>(pedges, gcnt, ccnt, clists);

    bgather_kernel<<<NPART * NCHUNKS, 1024, 0, stream>>>(
        clists, ccnt, count, h, b_conv, prelu_a, agg);

    gemm2_kernel<<<(N_NODES + 63) / 64, 256, 0, stream>>>(agg, fragW2, b_lin, out);
}

// Round 9
// 379.830 us; speedup vs baseline: 1.1753x; 1.1753x over previous
//
#include <hip/hip_runtime.h>

#define N_NODES 100000
#define E_EDGES 1600000
#define INDIM 256
#define HID 128
#define CAP 64          // fixed bucket capacity (max degree ~40 for this fixed graph)
#define NPART 8
#define PART_SZ 12500   // N_NODES / NPART
#define ECAP 32768      // per (xcd,part) sub-list capacity; expected ~25000
#define PA_BLOCKS 1563  // 400128 threads x 4 rounds covers 1.6M edges
#define PA_STRIDE (PA_BLOCKS * 256)
#define G1_BLOCKS 1563  // gemm1: ceil(100000/64)
#define PB_BLOCKS 1024  // partb: 128 block-slots x 8 partitions

typedef __attribute__((ext_vector_type(8))) short s16x8;
typedef __attribute__((ext_vector_type(4))) float f32x4;
typedef __attribute__((ext_vector_type(4))) unsigned int u32x4;

// ---- bf16 helpers (explicit RNE, bit-level) ----
__device__ __forceinline__ unsigned short cvt_bf16(float f) {
    unsigned int u = __float_as_uint(f);
    u += 0x7FFFu + ((u >> 16) & 1u);
    return (unsigned short)(u >> 16);
}
__device__ __forceinline__ float bf16_to_f(unsigned short s) {
    return __uint_as_float(((unsigned int)s) << 16);
}

// ---------------- parta (+ fused weight prep in first 256 blocks) ----------------
// Single scan of the edge list; packs (local_dst<<17 | src) into 64 sub-lists
// [xcd][part]. Wave ballot aggregation -> 8 LDS atomics -> 8 global atomics per
// block on XCD-local counters. NO count atomics here (they cost ~102MB of
// dirty-line writes, measured round 7 — pay that toll exactly once, in partb).
__global__ __launch_bounds__(256) void parta_kernel(const int* __restrict__ src,
                                                    const int* __restrict__ dst,
                                                    int* __restrict__ gcnt,
                                                    unsigned int* __restrict__ pedges,
                                                    const float* __restrict__ Wc,
                                                    const float* __restrict__ Wl,
                                                    unsigned short* __restrict__ f1,
                                                    unsigned short* __restrict__ f2) {
    __shared__ int sCount[8];
    __shared__ int sBase[8];
    const int tid = threadIdx.x;

    // fused prep: blocks 0..255 also reorder weights to fragment layout
    if (blockIdx.x < 256) {
        int pt = blockIdx.x * 256 + tid;  // 0..65535
        if (pt < 32768) {
            int j = pt & 7, L = (pt >> 3) & 63, t = (pt >> 9) & 7, c = pt >> 12;
            int k = c * 32 + ((L >> 4) * 8) + j;
            int n = t * 16 + (L & 15);
            f1[pt] = cvt_bf16(Wc[k * 128 + n]);
        } else {
            int u = pt - 32768;
            int j = u & 7, L = (u >> 3) & 63, t = (u >> 9) & 15, c = u >> 13;
            int k = c * 32 + ((L >> 4) * 8) + j;
            int n = t * 16 + (L & 15);
            f2[u] = cvt_bf16(Wl[k * 256 + n]);
        }
    }

    if (tid < 8) sCount[tid] = 0;
    __syncthreads();
    const int lane = tid & 63;
    const int t0 = blockIdx.x * 256 + tid;
    const int xcd = blockIdx.x & 7;

    unsigned int pk[4];
    int pp[4];
    int lo[4];
#pragma unroll
    for (int r = 0; r < 4; ++r) {
        int e = t0 + r * PA_STRIDE;
        bool valid = e < E_EDGES;
        int d = 0, s = 0;
        if (valid) {
            d = __builtin_nontemporal_load(dst + e);
            s = __builtin_nontemporal_load(src + e);
        }
        int p = valid ? d / PART_SZ : 8;
        unsigned long long mask_p = 0ull;
#pragma unroll
        for (int v = 0; v < 8; ++v) {
            unsigned long long mv = __ballot(p == v);
            if (p == v) mask_p = mv;
        }
        int off = __popcll(mask_p & ((1ull << lane) - 1ull));
        int ldr = (mask_p == 0ull) ? 0 : (__ffsll(mask_p) - 1);
        int wbase = 0;
        if (valid && lane == ldr) wbase = atomicAdd(&sCount[p], __popcll(mask_p));
        wbase = __shfl(wbase, ldr);
        pp[r] = p;
        lo[r] = wbase + off;
        pk[r] = ((unsigned int)(d - p * PART_SZ) << 17) | (unsigned int)s;
    }
    __syncthreads();
    if (tid < 8) sBase[tid] = atomicAdd(&gcnt[xcd * 8 + tid], sCount[tid]);
    __syncthreads();
#pragma unroll
    for (int r = 0; r < 4; ++r) {
        if (pp[r] < 8) {
            int pos = sBase[pp[r]] + lo[r];
            if (pos < ECAP)
                __builtin_nontemporal_store(pk[r],
                    pedges + (size_t)(xcd * 8 + pp[r]) * ECAP + pos);
        }
    }
}

// ---------------- fat: gemm1 (blocks 0..1562) || partb (blocks 1563..2586) ----------
// gemm1: h_bf16 = bf16(x) @ bf16(W_conv).  partb: XCD-local count+bin from the
// partitioned edge lists. partb's atomic/scatter latency hides under gemm1.
// (Round-3 pairing: measured 114us combined, beats serial 70+74.)
__global__ __launch_bounds__(256) void fat_kernel(const float* __restrict__ x,
                                                  const unsigned short* __restrict__ fragW,
                                                  unsigned short* __restrict__ h,
                                                  const unsigned int* __restrict__ pedges,
                                                  const int* __restrict__ gcnt,
                                                  int* __restrict__ count,
                                                  int* __restrict__ bucket) {
    __shared__ __align__(16) unsigned short xs[64 * 48];
    const int tid = threadIdx.x;

    if (blockIdx.x < G1_BLOCKS) {
        // ---- gemm1 ----
        const int r0 = blockIdx.x * 64;
        const int w = tid >> 6, lane = tid & 63;
        const int q = lane >> 4, m = lane & 15;
        const int srow = tid >> 2, skg = tid & 3;

        f32x4 acc[8];
#pragma unroll
        for (int t = 0; t < 8; ++t) acc[t] = (f32x4){0.f, 0.f, 0.f, 0.f};

        const s16x8* fwv = (const s16x8*)fragW;

        for (int c = 0; c < 8; ++c) {
            int gr = r0 + srow;
            f32x4 v0 = (f32x4){0.f, 0.f, 0.f, 0.f}, v1 = v0;
            if (gr < N_NODES) {
                const f32x4* p = (const f32x4*)&x[(size_t)gr * INDIM + c * 32 + skg * 8];
                v0 = __builtin_nontemporal_load(p);
                v1 = __builtin_nontemporal_load(p + 1);
            }
            uint4 pk;
            pk.x = ((unsigned)cvt_bf16(v0.y) << 16) | cvt_bf16(v0.x);
            pk.y = ((unsigned)cvt_bf16(v0.w) << 16) | cvt_bf16(v0.z);
            pk.z = ((unsigned)cvt_bf16(v1.y) << 16) | cvt_bf16(v1.x);
            pk.w = ((unsigned)cvt_bf16(v1.w) << 16) | cvt_bf16(v1.z);
            *(uint4*)&xs[srow * 48 + skg * 8] = pk;
            __syncthreads();

            s16x8 a = *(const s16x8*)&xs[(w * 16 + m) * 48 + q * 8];
#pragma unroll
            for (int t = 0; t < 8; ++t) {
                s16x8 b = fwv[(c * 8 + t) * 64 + lane];
                acc[t] = __builtin_amdgcn_mfma_f32_16x16x32_bf16(a, b, acc[t], 0, 0, 0);
            }
            __syncthreads();
        }

        const int row_base = r0 + w * 16 + q * 4;
#pragma unroll
        for (int t = 0; t < 8; ++t) {
#pragma unroll
            for (int r = 0; r < 4; ++r) {
                int row = row_base + r;
                if (row < N_NODES)
                    __builtin_nontemporal_store(cvt_bf16(acc[t][r]),
                        h + (size_t)row * HID + t * 16 + m);
            }
        }
    } else {
        // ---- partb ----
        const int part = blockIdx.x & 7;                  // == actual XCD (round-robin)
        const int bslot = (blockIdx.x - G1_BLOCKS) >> 3;  // 0..127
#pragma unroll
        for (int xx = 0; xx < 8; ++xx) {
            int n = gcnt[xx * 8 + part];
            if (n > ECAP) n = ECAP;
            const unsigned int* lst = pedges + (size_t)(xx * 8 + part) * ECAP;
            for (int i = bslot * 256 + tid; i < n; i += (PB_BLOCKS / 8) * 256) {
                unsigned int v = __builtin_nontemporal_load(lst + i);
                int s = (int)(v & 0x1FFFFu);
                int d = part * PART_SZ + (int)(v >> 17);
                int slot = atomicAdd(&count[d], 1);
                if (slot < CAP) bucket[d * CAP + slot] = s;
            }
        }
    }
}

// ---------------- per-node gather body (shared by gg and legacy gather) ----------
// wave = 1 node; 4 groups of 16 lanes; per iteration 8 edges (two independent
// uint4 row loads in flight per lane). Returns packed bias+PReLU bf16 in o[4]
// for g==0 lanes. dinv folded in as rsqrt(count+1).
__device__ __forceinline__ void gather_node(int wid, int lane, int g, int l,
                                            const int* __restrict__ bucket,
                                            const int* __restrict__ count,
                                            const uint4* __restrict__ hp4,
                                            const float* bc, float a,
                                            unsigned int* o) {
    const int raw = count[wid];
    const float dn = rsqrtf((float)(raw + 1));
    int deg = raw > CAP ? CAP : raw;

    int s_l = wid;
    float dv_l = 0.f;
    if (lane < deg) {
        s_l = bucket[wid * CAP + lane];
        dv_l = rsqrtf((float)(count[s_l] + 1));
    }

    float acc[8];
    {   // self-loop: counted once via group 0
        uint4 hv = hp4[(size_t)wid * 16 + l];
        float w0 = (g == 0) ? dn * dn : 0.f;
        const unsigned int* pv = (const unsigned int*)&hv;
#pragma unroll
        for (int k = 0; k < 4; ++k) {
            acc[2 * k]     = w0 * bf16_to_f((unsigned short)(pv[k] & 0xFFFF));
            acc[2 * k + 1] = w0 * bf16_to_f((unsigned short)(pv[k] >> 16));
        }
    }

    for (int j = 0; j < deg; j += 8) {
        int e0 = j + g;                       // <= 63 for deg<=64
        int e1 = j + 4 + g;
        int s0 = __shfl(s_l, e0);
        int s1 = __shfl(s_l, e1);
        float w0 = __shfl(dv_l, e0) * dn;     // 0 for e >= deg
        float w1 = __shfl(dv_l, e1) * dn;
        uint4 hv0 = hp4[(size_t)s0 * 16 + l];
        uint4 hv1 = hp4[(size_t)s1 * 16 + l];
        const unsigned int* p0 = (const unsigned int*)&hv0;
        const unsigned int* p1 = (const unsigned int*)&hv1;
#pragma unroll
        for (int k = 0; k < 4; ++k) {
            acc[2 * k]     += w0 * bf16_to_f((unsigned short)(p0[k] & 0xFFFF));
            acc[2 * k + 1] += w0 * bf16_to_f((unsigned short)(p0[k] >> 16));
        }
#pragma unroll
        for (int k = 0; k < 4; ++k) {
            acc[2 * k]     += w1 * bf16_to_f((unsigned short)(p1[k] & 0xFFFF));
            acc[2 * k + 1] += w1 * bf16_to_f((unsigned short)(p1[k] >> 16));
        }
    }

    // sum the 4 group-partials (features 8l..8l+7 live in lanes l,l+16,l+32,l+48)
#pragma unroll
    for (int k = 0; k < 8; ++k) {
        acc[k] += __shfl_xor(acc[k], 16);
        acc[k] += __shfl_xor(acc[k], 32);
    }

#pragma unroll
    for (int k = 0; k < 4; ++k) {
        float ox = acc[2 * k] + bc[2 * k];
        float oy = acc[2 * k + 1] + bc[2 * k + 1];
        ox = ox >= 0.f ? ox : a * ox;
        oy = oy >= 0.f ? oy : a * oy;
        o[k] = ((unsigned)cvt_bf16(oy) << 16) | cvt_bf16(ox);
    }
}

// ---------------- gg: fused gather + gemm2 (ws-h path) ----------------
// Block = 64 nodes, 16 waves. Phase A: proven wave-per-node gather (4 nodes per
// wave; resident waves/CU == round-3 gather) writing bf16 rows into LDS in the
// gemm2 staging layout [4][64][48]. Phase B: gemm2 MFMA from LDS, store out.
// Saves agg 25.6MB write + 25.6MB read + a launch; phase-B MFMA of early blocks
// overlaps phase-A load stalls of later blocks across the CU.
__global__ __launch_bounds__(1024) void gg_kernel(const int* __restrict__ bucket,
                                                  const int* __restrict__ count,
                                                  const unsigned short* __restrict__ h,
                                                  const float* __restrict__ b_conv,
                                                  const float* __restrict__ prelu_a,
                                                  const unsigned short* __restrict__ fragW,
                                                  const float* __restrict__ b_lin,
                                                  float* __restrict__ out) {
    __shared__ __align__(16) unsigned short xs[4 * 64 * 48];   // 24.6 KB
    const int tid = threadIdx.x;
    const int wv = tid >> 6;          // 0..15
    const int lane = tid & 63;
    const int g = lane >> 4;
    const int l = lane & 15;
    const int r0 = blockIdx.x * 64;
    const uint4* hp4 = (const uint4*)h;

    const float a = prelu_a[0];
    float bc[8];
    {
        float4 b0 = *(const float4*)&b_conv[l * 8];
        float4 b1 = *(const float4*)&b_conv[l * 8 + 4];
        bc[0] = b0.x; bc[1] = b0.y; bc[2] = b0.z; bc[3] = b0.w;
        bc[4] = b1.x; bc[5] = b1.y; bc[6] = b1.z; bc[7] = b1.w;
    }

    // ---- phase A: gather 4 nodes per wave into LDS staging layout ----
#pragma unroll
    for (int k = 0; k < 4; ++k) {
        const int n = wv * 4 + k;           // local row 0..63
        const int wid = r0 + n;
        if (wid < N_NODES) {
            unsigned int o[4];
            gather_node(wid, lane, g, l, bucket, count, hp4, bc, a, o);
            if (g == 0) {
                // features 8l..8l+7 -> chunk c = l>>2, within-chunk (l&3)*8
                uint4 ov;
                ov.x = o[0]; ov.y = o[1]; ov.z = o[2]; ov.w = o[3];
                *(uint4*)&xs[((l >> 2) * 64 + n) * 48 + (l & 3) * 8] = ov;
            }
        }
    }
    __syncthreads();

    // ---- phase B: gemm2 from LDS ----
    const int q = g, m = l;
    const int rg = wv & 3;              // row-group 0..3
    const int cg = wv >> 2;             // col-group 0..3 (4 tiles each)
    f32x4 acc[4];
#pragma unroll
    for (int t = 0; t < 4; ++t) acc[t] = (f32x4){0.f, 0.f, 0.f, 0.f};

    const s16x8* fwv = (const s16x8*)fragW;
#pragma unroll
    for (int c = 0; c < 4; ++c) {
        s16x8 av = *(const s16x8*)&xs[(c * 64 + rg * 16 + m) * 48 + q * 8];
#pragma unroll
        for (int t = 0; t < 4; ++t) {
            s16x8 b = fwv[(c * 16 + cg * 4 + t) * 64 + lane];
            acc[t] = __builtin_amdgcn_mfma_f32_16x16x32_bf16(av, b, acc[t], 0, 0, 0);
        }
    }

    const int row_base = r0 + rg * 16 + q * 4;
#pragma unroll
    for (int t = 0; t < 4; ++t) {
        int col = (cg * 4 + t) * 16 + m;
        float bias = b_lin[col];
#pragma unroll
        for (int r = 0; r < 4; ++r) {
            int row = row_base + r;
            if (row < N_NODES)
                __builtin_nontemporal_store(acc[t][r] + bias,
                    out + (size_t)row * INDIM + col);
        }
    }
}

// ---------------- legacy gather (h in d_out path) ----------------
__global__ __launch_bounds__(256) void gather_kernel(const int* __restrict__ bucket,
                                                     const int* __restrict__ count,
                                                     const unsigned short* __restrict__ h,
                                                     const float* __restrict__ b_conv,
                                                     const float* __restrict__ prelu_a,
                                                     unsigned short* __restrict__ agg) {
    const int part = blockIdx.x & 7;
    const int bidx = blockIdx.x >> 3;
    const int wv = threadIdx.x >> 6;
    const int wid = part * PART_SZ + bidx * 4 + wv;
    const int lane = threadIdx.x & 63;
    const int g = lane >> 4;
    const int l = lane & 15;

    const float a = prelu_a[0];
    float bc[8];
    {
        float4 b0 = *(const float4*)&b_conv[l * 8];
        float4 b1 = *(const float4*)&b_conv[l * 8 + 4];
        bc[0] = b0.x; bc[1] = b0.y; bc[2] = b0.z; bc[3] = b0.w;
        bc[4] = b1.x; bc[5] = b1.y; bc[6] = b1.z; bc[7] = b1.w;
    }
    unsigned int o[4];
    gather_node(wid, lane, g, l, bucket, count, (const uint4*)h, bc, a, o);
    if (g == 0) {
        uint4 ov;
        ov.x = o[0]; ov.y = o[1]; ov.z = o[2]; ov.w = o[3];
        ((uint4*)agg)[(size_t)wid * 16 + l] = ov;
    }
}

// ---------------- legacy GEMM2 ----------------
__global__ __launch_bounds__(256) void gemm2_kernel(const unsigned short* __restrict__ agg,
                                                    const unsigned short* __restrict__ fragW,
                                                    const float* __restrict__ b_lin,
                                                    float* __restrict__ out) {
    __shared__ __align__(16) unsigned short xs[64 * 48];
    const int tid = threadIdx.x;
    const int r0 = blockIdx.x * 64;
    const int w = tid >> 6, lane = tid & 63;
    const int q = lane >> 4, m = lane & 15;
    const int srow = tid >> 2, skg = tid & 3;

    f32x4 acc[16];
#pragma unroll
    for (int t = 0; t < 16; ++t) acc[t] = (f32x4){0.f, 0.f, 0.f, 0.f};

    const s16x8* fwv = (const s16x8*)fragW;
    const u32x4* aggv = (const u32x4*)agg;

    for (int c = 0; c < 4; ++c) {
        int gr = r0 + srow;
        u32x4 pk = (u32x4){0u, 0u, 0u, 0u};
        if (gr < N_NODES) pk = __builtin_nontemporal_load(&aggv[(size_t)gr * 16 + c * 4 + skg]);
        *(u32x4*)&xs[srow * 48 + skg * 8] = pk;
        __syncthreads();

        s16x8 av = *(const s16x8*)&xs[(w * 16 + m) * 48 + q * 8];
#pragma unroll
        for (int t = 0; t < 16; ++t) {
            s16x8 b = fwv[(c * 16 + t) * 64 + lane];
            acc[t] = __builtin_amdgcn_mfma_f32_16x16x32_bf16(av, b, acc[t], 0, 0, 0);
        }
        __syncthreads();
    }

    const int row_base = r0 + w * 16 + q * 4;
#pragma unroll
    for (int t = 0; t < 16; ++t) {
        float bias = b_lin[t * 16 + m];
#pragma unroll
        for (int r = 0; r < 4; ++r) {
            int row = row_base + r;
            if (row < N_NODES)
                __builtin_nontemporal_store(acc[t][r] + bias,
                    out + (size_t)row * INDIM + t * 16 + m);
        }
    }
}

extern "C" void kernel_launch(void* const* d_in, const int* in_sizes, int n_in,
                              void* d_out, int out_size, void* d_ws, size_t ws_size,
                              hipStream_t stream) {
    const float* x       = (const float*)d_in[0];
    const int*   eidx    = (const int*)d_in[1];
    const float* W_conv  = (const float*)d_in[2];
    const float* b_conv  = (const float*)d_in[3];
    const float* prelu_a = (const float*)d_in[4];
    const float* W_lin   = (const float*)d_in[5];
    const float* b_lin   = (const float*)d_in[6];
    float* out = (float*)d_out;

    const int* src = eidx;
    const int* dst = eidx + E_EDGES;

    char* base = (char*)d_ws;
    const size_t SZ_BUCKET = (size_t)N_NODES * CAP * 4;   // 25.6 MB
    const size_t SZ_H      = (size_t)N_NODES * HID * 2;   // 25.6 MB
    const size_t SZ_PED    = (size_t)64 * ECAP * 4;       // 8.39 MB
    const size_t NEED = SZ_BUCKET + SZ_H + SZ_PED + 100352 * 4 + 65536 * 2 + 256;

    if (ws_size >= NEED) {
        // -------- fused path: h in workspace, gather+gemm2 fused --------
        int* bucket = (int*)base;
        unsigned short* h = (unsigned short*)(base + SZ_BUCKET);
        unsigned int* pedges = (unsigned int*)(base + SZ_BUCKET + SZ_H);
        int* count = (int*)(base + SZ_BUCKET + SZ_H + SZ_PED);
        int* gcnt  = count + 100000;
        unsigned short* fragW1 = (unsigned short*)(count + 100352);
        unsigned short* fragW2 = fragW1 + 32768;

        hipMemsetAsync(count, 0, (size_t)100352 * sizeof(int), stream);

        parta_kernel<<<PA_BLOCKS, 256, 0, stream>>>(src, dst, gcnt, pedges,
                                                    W_conv, W_lin, fragW1, fragW2);

        fat_kernel<<<G1_BLOCKS + PB_BLOCKS, 256, 0, stream>>>(x, fragW1, h,
                                                              pedges, gcnt, count, bucket);

        gg_kernel<<<(N_NODES + 63) / 64, 1024, 0, stream>>>(
            bucket, count, h, b_conv, prelu_a, fragW2, b_lin, out);
    } else {
        // -------- legacy round-3 path: h in d_out, separate gather+gemm2 --------
        int* bucket = (int*)base;
        unsigned short* agg = (unsigned short*)(base + SZ_BUCKET);
        int* count = (int*)((char*)agg + SZ_H);
        int* gcnt  = count + 100000;
        unsigned short* fragW1 = (unsigned short*)(count + 100352);
        unsigned short* fragW2 = fragW1 + 32768;
        unsigned int* pedges = (unsigned int*)agg;   // dead before gather writes agg
        unsigned short* h = (unsigned short*)d_out;  // overwritten only by gemm2 (last)

        hipMemsetAsync(count, 0, (size_t)100352 * sizeof(int), stream);

        parta_kernel<<<PA_BLOCKS, 256, 0, stream>>>(src, dst, gcnt, pedges,
                                                    W_conv, W_lin, fragW1, fragW2);

        fat_kernel<<<G1_BLOCKS + PB_BLOCKS, 256, 0, stream>>>(x, fragW1, h,
                                                              pedges, gcnt, count, bucket);

        gather_kernel<<<NPART * (PART_SZ / 4), 256, 0, stream>>>(
            bucket, count, h, b_conv, prelu_a, agg);

        gemm2_kernel<<<(N_NODES + 63) / 64, 256, 0, stream>>>(agg, fragW2, b_lin, out);
    }
}